// Round 16
// baseline (177.499 us; speedup 1.0000x reference)
//
#include <hip/hip_runtime.h>
#include <math.h>

#define BS 4
#define C 4
#define N 2048
#define D 16
#define KNN 32
#define M 64

typedef unsigned long long u64;
typedef unsigned int u32;
typedef unsigned short u16;
typedef float v2f __attribute__((ext_vector_type(2)));

// ---------------------------------------------------------------------------
// Kernel 1: exact 32-NN (sorted ascending, ties -> lower index) per (b,c,n).
// TWO rows per wave; 16 rows (same b,c) per 512-thread block.
// Both passes compute rowA+rowB dists as packed float2 (v_pk_mul/add_f32,
// per-half IEEE rounding == scalar -> bit-identical order).
// Pass 1: packed per-lane min of raw dists (float order valid: no NaNs; the
// only zero dist is self, +0). Pivot pd = 33rd-smallest of the 64 lane
// minima (interleaved float bitonic). Guarantee: >=33 keys have dist<=pd.
// Pass 2: ONE packed scan; exec-masked ballot-prefix compact into a SINGLE
// shared 128-slot buffer per wave: rowA from the front (ascending), rowB
// from the back (descending) -> LDS stays 40 KB = 4 blocks/CU (R15's
// per-row buffers cost 48 KB -> 3 blocks/CU, VALUBusy 87->66%).
// Rank-sort via broadcast ds_read + u64 compares (reversed indexing for B);
// ranks 1..32 store (rank 0 dropped = reference top-(k+1)). Exact serial
// fallback for BOTH rows when cntA+cntB>118 (~never; pad collision-safe).
// launch_bounds(512,6): VGPR cap ~85 (R12's (512,8) forced VGPR=32 -> 200 MB
// scratch spill). Block 0 additionally repacks aw4/sw4 (fused prep).
// Distance arithmetic replicates numpy f32 semantics bit-exactly:
//   inner = (x*x' + y*y') + z*z'   (sequential, no fma)
//   quad  = (x*x + y*y) + z*z
//   dist  = ((-2*inner) + quad_j) + quad_n
// ---------------------------------------------------------------------------

__device__ __forceinline__ u32 umin_u32(u32 a, u32 b) { return a < b ? a : b; }

#define DPP_MIN_STAGE(v, ctrl)                                                  \
    v = umin_u32(v, (u32)__builtin_amdgcn_update_dpp(                           \
                        (int)0xFFFFFFFF, (int)(v), (ctrl), 0xF, 0xF, false))

__device__ __forceinline__ u32 wave_min_dpp(u32 v) {
    DPP_MIN_STAGE(v, 0x111);
    DPP_MIN_STAGE(v, 0x112);
    DPP_MIN_STAGE(v, 0x114);
    DPP_MIN_STAGE(v, 0x118);
    DPP_MIN_STAGE(v, 0x142);
    DPP_MIN_STAGE(v, 0x143);
    return (u32)__builtin_amdgcn_readlane((int)v, 63);
}

#define DPP_ADD_STAGE(v, ctrl)                                                  \
    v += __int_as_float(__builtin_amdgcn_update_dpp(                            \
        0, __float_as_int(v), (ctrl), 0xF, 0xF, false))

__device__ __forceinline__ float wave_sum_dpp(float v) {
    DPP_ADD_STAGE(v, 0x111);
    DPP_ADD_STAGE(v, 0x112);
    DPP_ADD_STAGE(v, 0x114);
    DPP_ADD_STAGE(v, 0x118);
    DPP_ADD_STAGE(v, 0x142);
    DPP_ADD_STAGE(v, 0x143);
    return __int_as_float(__builtin_amdgcn_readlane(__float_as_int(v), 63));
}

__device__ __forceinline__ u32 mbcnt64(u64 m) {
    return __builtin_amdgcn_mbcnt_hi((u32)(m >> 32),
                                     __builtin_amdgcn_mbcnt_lo((u32)m, 0));
}

__device__ __forceinline__ float np_quad(float x, float y, float z) {
#pragma clang fp contract(off)
    float q = (x * x + y * y) + z * z;
    return q;
}

__device__ __forceinline__ float np_dist(const float4& me, const float4& p) {
#pragma clang fp contract(off)
    float inner = (me.x * p.x + me.y * p.y) + me.z * p.z;
    float dist  = ((-2.0f * inner) + p.w) + me.w;
    return dist;
}

// packed two-row distance; per-half rounding identical to np_dist
__device__ __forceinline__ v2f np_dist2(v2f mex, v2f mey, v2f mez, v2f mew,
                                        float4 p) {
#pragma clang fp contract(off)
    v2f t1 = mex * p.x;
    v2f t2 = mey * p.y;
    v2f s  = t1 + t2;
    v2f t3 = mez * p.z;
    v2f inner = s + t3;
    v2f a = (-2.0f) * inner;
    v2f b = a + p.w;
    v2f d = b + mew;
    return d;
}

__device__ __forceinline__ u32 flip_bits(float dist) {
    u32 b = __float_as_uint(dist);
    return b ^ (0x80000000u | (u32)((int)b >> 31));
}

__device__ __forceinline__ u64 dist_key(float dist, int j) {
    return ((u64)flip_bits(dist) << 32) | (u32)j;
}

// rank-sort survivors sl[0..cnt) ascending-stored and emit ranks 1..32
__device__ __forceinline__ void emit_rank(u64* sl, int cnt, int row, int lane,
                                          u16* __restrict__ edge_ws,
                                          float* __restrict__ dist_ws) {
    if (lane < 4) sl[cnt + lane] = ~0ull;   // pads for the unroll-4 overshoot
    u64 own1 = sl[lane];
    if (lane >= cnt) own1 = ~0ull;
    int r1 = 0;
    for (int i = 0; i < cnt; i += 4) {
        u64 s0 = sl[i], s1 = sl[i + 1], s2 = sl[i + 2], s3 = sl[i + 3];
        r1 += (s0 < own1) + (s1 < own1) + (s2 < own1) + (s3 < own1);
    }
    if (r1 >= 1 && r1 <= KNN) {
        u32 fk = (u32)(own1 >> 32);
        u32 bb = (fk & 0x80000000u) ? (fk ^ 0x80000000u) : ~fk;
        edge_ws[(size_t)row * KNN + r1 - 1] = (u16)(u32)own1;
        dist_ws[(size_t)row * KNN + r1 - 1] = __uint_as_float(bb);
    }
    if (cnt > 64) {   // uncommon (~1%), wave-uniform
        u64 own2 = (64 + lane < cnt) ? sl[64 + lane] : ~0ull;
        int r2 = 0;
        for (int i = 0; i < cnt; i += 4) {
            u64 s0 = sl[i], s1 = sl[i + 1], s2 = sl[i + 2], s3 = sl[i + 3];
            r2 += (s0 < own2) + (s1 < own2) + (s2 < own2) + (s3 < own2);
        }
        if (r2 >= 1 && r2 <= KNN) {
            u32 fk = (u32)(own2 >> 32);
            u32 bb = (fk & 0x80000000u) ? (fk ^ 0x80000000u) : ~fk;
            edge_ws[(size_t)row * KNN + r2 - 1] = (u16)(u32)own2;
            dist_ws[(size_t)row * KNN + r2 - 1] = __uint_as_float(bb);
        }
    }
}

// same, for survivors stored descending from sl[127] (rowB of the shared buf)
__device__ __forceinline__ void emit_rank_rev(u64* sl, int cnt, int row, int lane,
                                              u16* __restrict__ edge_ws,
                                              float* __restrict__ dist_ws) {
    if (lane < 4) sl[127 - (cnt + lane)] = ~0ull;   // pads
    u64 own1 = sl[127 - lane];
    if (lane >= cnt) own1 = ~0ull;
    int r1 = 0;
    for (int i = 0; i < cnt; i += 4) {
        u64 s0 = sl[127 - i], s1 = sl[126 - i], s2 = sl[125 - i], s3 = sl[124 - i];
        r1 += (s0 < own1) + (s1 < own1) + (s2 < own1) + (s3 < own1);
    }
    if (r1 >= 1 && r1 <= KNN) {
        u32 fk = (u32)(own1 >> 32);
        u32 bb = (fk & 0x80000000u) ? (fk ^ 0x80000000u) : ~fk;
        edge_ws[(size_t)row * KNN + r1 - 1] = (u16)(u32)own1;
        dist_ws[(size_t)row * KNN + r1 - 1] = __uint_as_float(bb);
    }
    if (cnt > 64) {
        u64 own2 = (64 + lane < cnt) ? sl[127 - 64 - lane] : ~0ull;
        int r2 = 0;
        for (int i = 0; i < cnt; i += 4) {
            u64 s0 = sl[127 - i], s1 = sl[126 - i], s2 = sl[125 - i], s3 = sl[124 - i];
            r2 += (s0 < own2) + (s1 < own2) + (s2 < own2) + (s3 < own2);
        }
        if (r2 >= 1 && r2 <= KNN) {
            u32 fk = (u32)(own2 >> 32);
            u32 bb = (fk & 0x80000000u) ? (fk ^ 0x80000000u) : ~fk;
            edge_ws[(size_t)row * KNN + r2 - 1] = (u16)(u32)own2;
            dist_ws[(size_t)row * KNN + r2 - 1] = __uint_as_float(bb);
        }
    }
}

// register-light exact fallback (~never): 33 rescan-extract rounds
__device__ __attribute__((noinline)) void slow_row(const float4* sp, float4 me,
                                                   int row, int lane,
                                                   u16* __restrict__ edge_ws,
                                                   float* __restrict__ dist_ws) {
    u64 thr = 0ull;   // all real keys are > 0 (flip==0 would require NaN dist)
    for (int s = 0; s <= KNN; ++s) {
        u64 best = ~0ull;
        for (int jj = 0; jj < 32; ++jj) {
            int j = jj * 64 + lane;
            u64 x = dist_key(np_dist(me, sp[j]), j);
            if (x > thr && x < best) best = x;
        }
        u32 bh = (u32)(best >> 32);
        u32 rh = wave_min_dpp(bh);
        u32 bl = (bh == rh) ? (u32)best : 0xFFFFFFFFu;
        u32 rl = wave_min_dpp(bl);
        thr = ((u64)rh << 32) | rl;
        if (s >= 1 && lane == s - 1) {
            u32 bb = (rh & 0x80000000u) ? (rh ^ 0x80000000u) : ~rh;
            edge_ws[(size_t)row * KNN + s - 1] = (u16)rl;
            dist_ws[(size_t)row * KNN + s - 1] = __uint_as_float(bb);
        }
    }
}

__global__ __launch_bounds__(512, 6) void knn_kernel(const float* __restrict__ pos,
                                                     u16* __restrict__ edge_ws,
                                                     float* __restrict__ dist_ws,
                                                     const float* __restrict__ aw,
                                                     const float* __restrict__ sw,
                                                     float* __restrict__ aw4,
                                                     float* __restrict__ sw4) {
    __shared__ float4 sp[N];          // 32 KB
    __shared__ u64 slots[8][128];     // 8 KB: rowA front / rowB back, per wave
    const int tid  = threadIdx.x;
    const int lane = tid & 63;
    const int wave = tid >> 6;          // 0..7
    const int rb   = blockIdx.x * 16;   // 16 rows per block, same (b,c)
    const int bc   = rb >> 11;

    const float* posr = pos + (size_t)bc * (N * 3);
    for (int j = tid; j < N; j += 512) {
        float x = posr[3 * j], y = posr[3 * j + 1], z = posr[3 * j + 2];
        sp[j] = make_float4(x, y, z, np_quad(x, y, z));
    }

    // fused prep (block 0 only): repack weights into [f/4][m][f%4]
    if (blockIdx.x == 0) {
#pragma unroll
        for (int it = 0; it < 16; ++it) {
            int i = it * 512 + tid;           // i = f*64 + m
            int f = i >> 6, mm = i & 63;
            int idx = (f >> 2) * 256 + mm * 4 + (f & 3);
            aw4[idx] = aw[mm * 128 + f];
            sw4[idx] = sw[i];
        }
    }
    __syncthreads();

    const int rowA = rb + wave * 2, rowB = rowA + 1;
    const int nA = rowA & (N - 1), nB = nA + 1;
    const float4 meA = sp[nA];
    const float4 meB = sp[nB];
    const v2f mex = {meA.x, meB.x};
    const v2f mey = {meA.y, meB.y};
    const v2f mez = {meA.z, meB.z};
    const v2f mew = {meA.w, meB.w};

    // ---- pass 1: packed per-lane float min of dists, both rows ----
    float mnA = __builtin_inff(), mnB = __builtin_inff();
#pragma unroll 8
    for (int jj = 0; jj < 32; ++jj) {
        int j = jj * 64 + lane;
        v2f d = np_dist2(mex, mey, mez, mew, sp[j]);
        mnA = fminf(mnA, d.x);
        mnB = fminf(mnB, d.y);
    }

    // ---- pivots: 33rd-smallest lane min (interleaved float bitonic) ----
    float vA = mnA, vB = mnB;
#pragma unroll
    for (int k = 2; k <= 64; k <<= 1) {
#pragma unroll
        for (int j = k >> 1; j > 0; j >>= 1) {
            float oA = __int_as_float(__shfl_xor(__float_as_int(vA), j));
            float oB = __int_as_float(__shfl_xor(__float_as_int(vB), j));
            bool keepmin = (((lane & k) == 0) == ((lane & j) == 0));
            vA = ((oA < vA) == keepmin) ? oA : vA;
            vB = ((oB < vB) == keepmin) ? oB : vB;
        }
    }
    float pdA = __int_as_float(__builtin_amdgcn_readlane(__float_as_int(vA), 32));
    float pdB = __int_as_float(__builtin_amdgcn_readlane(__float_as_int(vB), 32));

    // ---- pass 2: ONE packed scan; A compacts forward, B backward ----
    u64* sl = slots[wave];
    u32 baseA = 0, baseB = 0;
#pragma unroll 2
    for (int jj = 0; jj < 32; ++jj) {
        int j = jj * 64 + lane;
        v2f d = np_dist2(mex, mey, mez, mew, sp[j]);
        bool sA = d.x <= pdA;
        bool sB = d.y <= pdB;
        u64 mA = __ballot(sA);
        u64 mB = __ballot(sB);
        u32 posA = baseA + mbcnt64(mA);
        u32 posB = baseB + mbcnt64(mB);
        if (sA && posA < 128) sl[posA] = ((u64)flip_bits(d.x) << 32) | (u32)j;
        if (sB && posB < 128) sl[127 - posB] = ((u64)flip_bits(d.y) << 32) | (u32)j;
        baseA += (u32)__popcll(mA);
        baseB += (u32)__popcll(mB);
    }

    if (baseA + baseB <= 118) {   // pads collision-free below 120
        emit_rank(sl, (int)baseA, rowA, lane, edge_ws, dist_ws);
        emit_rank_rev(sl, (int)baseB, rowB, lane, edge_ws, dist_ws);
    } else {
        slow_row(sp, meA, rowA, lane, edge_ws, dist_ws);
        slow_row(sp, meB, rowB, lane, edge_ws, dist_ws);
    }
}

// ---------------------------------------------------------------------------
// Kernel 2: angle features + gate + gated aggregation + two 128->64 matvecs.
// One wave per (b,n); 8 consecutive n (same b) per 512-thread block.
// All intermediates wave-private in LDS -> only ONE barrier (outv transpose).
// Phase C: float4 weights from global (VMEM pipe) x float4 theta/h broadcast
// from LDS, INTERLEAVED (R15's split-pass variant regressed ~6 us).
// ---------------------------------------------------------------------------
__global__ __launch_bounds__(512) void conv_kernel(
    const float* __restrict__ pos, const float* __restrict__ node_fea,
    const float* __restrict__ node_mask, const float* __restrict__ aw4,
    const float* __restrict__ sw4, const float* __restrict__ w1,
    const float* __restrict__ w2, const u16* __restrict__ edge_ws,
    const float* __restrict__ dist_ws, float* __restrict__ out) {
    __shared__ __align__(16) float theta_lds[8][128];  // [wave][f], f=kk*4+cc
    __shared__ float gate_lds[8][128];                 // [wave][cc*32+kk]
    __shared__ u16   edge_lds[8][128];                 // [wave][cc*32+kk]
    __shared__ __align__(16) float h_lds[8][128];      // [wave][f], f=cc*32+..
    __shared__ float gsum_lds[8][4];                   // [wave][cc]
    __shared__ float outv[8][65];                      // [n-offset][m], padded

    const int tid  = threadIdx.x;
    const int lane = tid & 63;
    const int wave = tid >> 6;             // 0..7

    const int row0 = blockIdx.x * 8;   // (b,n) row base, same b across block
    const int b    = row0 >> 11;
    const int n0   = row0 & (N - 1);
    const int row  = row0 + wave;
    const int n    = row & (N - 1);
    const float mval = node_mask[b * N + n];

    // gate scalar S = sum_m relu(w1[m]) * w2[m]
    float S = wave_sum_dpp(fmaxf(w1[lane], 0.f) * w2[lane]);

    // ---- Phase A: per (cc,kk) pair: direction, theta, gate (wave-private) ----
#pragma unroll
    for (int it = 0; it < 2; ++it) {
        int p  = it * 64 + lane;
        int cc = p >> 5, kk = p & 31;
        int rowc = (b * C + cc) * N + n;
        int e      = edge_ws[(size_t)rowc * KNN + kk];
        float dist = dist_ws[(size_t)rowc * KNN + kk];
        const float* pp = pos + (size_t)rowc * 3;
        const float* qp = pos + ((size_t)(b * C + cc) * N + e) * 3;
        float dx = qp[0] - pp[0], dy = qp[1] - pp[1], dz = qp[2] - pp[2];
        float nrm = fmaxf(sqrtf(dx * dx + dy * dy + dz * dz), 1e-12f);
        float inv = 1.0f / nrm;
        dx *= inv; dy *= inv; dz *= inv;
        int src = lane & 32;   // lane holding kk==0 for this cc-group
        float n0x = __shfl(dx, src), n0y = __shfl(dy, src), n0z = __shfl(dz, src);
        float cosv = (kk == 0) ? 1.f : (dx * n0x + dy * n0y + dz * n0z);
        theta_lds[wave][kk * 4 + cc] = cosv * mval;

        float g = fmaxf(dist * S, 0.f) * mval;
        float gate = 1.f / (1.f + expf(-g));
        gate_lds[wave][cc * 32 + kk] = gate;
        edge_lds[wave][cc * 32 + kk] = (u16)e;
        float gs = gate;
#pragma unroll
        for (int off = 1; off < 32; off <<= 1) gs += __shfl_xor(gs, off);
        if (kk == 0) gsum_lds[wave][cc] = gs;
    }

    // ---- Phase B: h[f] = sum_k gate * fea_cat (all 64 lanes gather) ----
    {
        int cc = lane >> 4, dd = lane & 15;
        const float* nf = node_fea + (size_t)(b * C + cc) * N * D;
        float own = nf[(size_t)n * D + dd];
        h_lds[wave][cc * 32 + dd] = own * mval * gsum_lds[wave][cc];
        float acc = 0.f;
#pragma unroll
        for (int k = 0; k < 32; ++k) {
            int e = edge_lds[wave][cc * 32 + k];
            acc += gate_lds[wave][cc * 32 + k] * nf[(size_t)e * D + dd];
        }
        h_lds[wave][cc * 32 + 16 + dd] = acc * mval;
    }

    // ---- Phase C: m = lane; two 128->64 matvecs (float4, interleaved) ----
    {
        const float4* wa4 = (const float4*)aw4;
        const float4* wv4 = (const float4*)sw4;
        const float4* th4 = (const float4*)(&theta_lds[wave][0]);
        const float4* hh4 = (const float4*)(&h_lds[wave][0]);
        float fs = 0.f, fe = 0.f;
#pragma unroll 4
        for (int f4 = 0; f4 < 32; ++f4) {
            float4 wa = wa4[f4 * 64 + lane];
            float4 wv = wv4[f4 * 64 + lane];
            float4 tv = th4[f4];
            float4 hv = hh4[f4];
            fs += wa.x * tv.x + wa.y * tv.y + wa.z * tv.z + wa.w * tv.w;
            fe += wv.x * hv.x + wv.y * hv.y + wv.z * hv.z + wv.w * hv.w;
        }
        float v = fs + fe;
        v = (v > 0.f) ? v : 0.01f * v;
        outv[wave][lane] = v * mval;
    }
    __syncthreads();   // the only cross-wave handoff (outv transpose)

    // store: thread t -> m = t>>3, n-offset j = t&7
    {
        int m = tid >> 3, j = tid & 7;
        out[((size_t)(b * 64 + m)) * N + n0 + j] = outv[j][m];
    }
}

// ---------------------------------------------------------------------------
extern "C" void kernel_launch(void* const* d_in, const int* in_sizes, int n_in,
                              void* d_out, int out_size, void* d_ws, size_t ws_size,
                              hipStream_t stream) {
    const float* pos       = (const float*)d_in[0];
    const float* node_fea  = (const float*)d_in[1];
    const float* node_mask = (const float*)d_in[2];
    const float* aw        = (const float*)d_in[3];
    const float* sw        = (const float*)d_in[4];
    const float* w1        = (const float*)d_in[5];
    const float* w2        = (const float*)d_in[6];
    float* out = (float*)d_out;

    // ws: dist f32 4 MB | edge u16 2 MB | aw4 32 KB | sw4 32 KB  (~6.1 MB)
    float* dist_ws = (float*)d_ws;
    u16*   edge_ws = (u16*)((char*)d_ws + 4u * 1024 * 1024);
    float* aw4     = (float*)((char*)d_ws + 6u * 1024 * 1024);
    float* sw4     = (float*)((char*)d_ws + 6u * 1024 * 1024 + 32u * 1024);

    knn_kernel<<<BS * C * N / 16, 512, 0, stream>>>(pos, edge_ws, dist_ws,
                                                    aw, sw, aw4, sw4);
    conv_kernel<<<BS * N / 8, 512, 0, stream>>>(pos, node_fea, node_mask, aw4, sw4,
                                                w1, w2, edge_ws, dist_ws, out);
}

// Round 17
// 144.738 us; speedup vs baseline: 1.2263x; 1.2263x over previous
//
#include <hip/hip_runtime.h>
#include <math.h>

#define BS 4
#define C 4
#define N 2048
#define D 16
#define KNN 32
#define M 64

typedef unsigned long long u64;
typedef unsigned int u32;
typedef unsigned short u16;
typedef float v2f __attribute__((ext_vector_type(2)));

// ---------------------------------------------------------------------------
// Kernel 1: exact 32-NN (sorted ascending, ties -> lower index) per (b,c,n).
// TWO rows per wave; 16 rows (same b,c) per 512-thread block.
// Both passes compute rowA+rowB dists as packed float2 (v_pk_mul/add_f32,
// per-half IEEE rounding == scalar -> bit-identical order).
// Pass 1: packed per-lane min of raw dists (float order valid: no NaNs; the
// only zero dist is self, +0). Pivot pd = 33rd-smallest of the 64 lane
// minima (interleaved float bitonic). Guarantee: >=33 keys have dist<=pd.
// Pass 2: ONE packed scan; exec-masked ballot-prefix compact into a SINGLE
// shared 128-slot buffer per wave (rowA front-ascending, rowB back-
// descending) -> LDS 40 KB = 4 blocks/CU. Fast path iff cntA+cntB<=121
// (pad-safe <=124). Fallback (R16 lesson: ~5-10% incidence, so it must be
// CHEAP): sequential per-row scalar re-compact into the full buffer (R14
// form, guard 124); slow_row only beyond that (~never).
// Rank-sort via broadcast ds_read + u64 compares; ranks 1..32 store (rank 0
// dropped = reference top-(k+1) semantics).
// launch_bounds(512,6): VGPR cap ~85 (R12's (512,8) forced VGPR=32 -> 200 MB
// scratch spill). Block 0 additionally repacks aw4/sw4 (fused prep).
// Distance arithmetic replicates numpy f32 semantics bit-exactly:
//   inner = (x*x' + y*y') + z*z'   (sequential, no fma)
//   quad  = (x*x + y*y) + z*z
//   dist  = ((-2*inner) + quad_j) + quad_n
// ---------------------------------------------------------------------------

__device__ __forceinline__ u32 umin_u32(u32 a, u32 b) { return a < b ? a : b; }

#define DPP_MIN_STAGE(v, ctrl)                                                  \
    v = umin_u32(v, (u32)__builtin_amdgcn_update_dpp(                           \
                        (int)0xFFFFFFFF, (int)(v), (ctrl), 0xF, 0xF, false))

__device__ __forceinline__ u32 wave_min_dpp(u32 v) {
    DPP_MIN_STAGE(v, 0x111);
    DPP_MIN_STAGE(v, 0x112);
    DPP_MIN_STAGE(v, 0x114);
    DPP_MIN_STAGE(v, 0x118);
    DPP_MIN_STAGE(v, 0x142);
    DPP_MIN_STAGE(v, 0x143);
    return (u32)__builtin_amdgcn_readlane((int)v, 63);
}

#define DPP_ADD_STAGE(v, ctrl)                                                  \
    v += __int_as_float(__builtin_amdgcn_update_dpp(                            \
        0, __float_as_int(v), (ctrl), 0xF, 0xF, false))

__device__ __forceinline__ float wave_sum_dpp(float v) {
    DPP_ADD_STAGE(v, 0x111);
    DPP_ADD_STAGE(v, 0x112);
    DPP_ADD_STAGE(v, 0x114);
    DPP_ADD_STAGE(v, 0x118);
    DPP_ADD_STAGE(v, 0x142);
    DPP_ADD_STAGE(v, 0x143);
    return __int_as_float(__builtin_amdgcn_readlane(__float_as_int(v), 63));
}

__device__ __forceinline__ u32 mbcnt64(u64 m) {
    return __builtin_amdgcn_mbcnt_hi((u32)(m >> 32),
                                     __builtin_amdgcn_mbcnt_lo((u32)m, 0));
}

__device__ __forceinline__ float np_quad(float x, float y, float z) {
#pragma clang fp contract(off)
    float q = (x * x + y * y) + z * z;
    return q;
}

__device__ __forceinline__ float np_dist(const float4& me, const float4& p) {
#pragma clang fp contract(off)
    float inner = (me.x * p.x + me.y * p.y) + me.z * p.z;
    float dist  = ((-2.0f * inner) + p.w) + me.w;
    return dist;
}

// packed two-row distance; per-half rounding identical to np_dist
__device__ __forceinline__ v2f np_dist2(v2f mex, v2f mey, v2f mez, v2f mew,
                                        float4 p) {
#pragma clang fp contract(off)
    v2f t1 = mex * p.x;
    v2f t2 = mey * p.y;
    v2f s  = t1 + t2;
    v2f t3 = mez * p.z;
    v2f inner = s + t3;
    v2f a = (-2.0f) * inner;
    v2f b = a + p.w;
    v2f d = b + mew;
    return d;
}

__device__ __forceinline__ u32 flip_bits(float dist) {
    u32 b = __float_as_uint(dist);
    return b ^ (0x80000000u | (u32)((int)b >> 31));
}

__device__ __forceinline__ u64 dist_key(float dist, int j) {
    return ((u64)flip_bits(dist) << 32) | (u32)j;
}

// rank-sort survivors sl[0..cnt) ascending-stored and emit ranks 1..32
__device__ __forceinline__ void emit_rank(u64* sl, int cnt, int row, int lane,
                                          u16* __restrict__ edge_ws,
                                          float* __restrict__ dist_ws) {
    if (lane < 4) sl[cnt + lane] = ~0ull;   // pads for the unroll-4 overshoot
    u64 own1 = sl[lane];
    if (lane >= cnt) own1 = ~0ull;
    int r1 = 0;
    for (int i = 0; i < cnt; i += 4) {
        u64 s0 = sl[i], s1 = sl[i + 1], s2 = sl[i + 2], s3 = sl[i + 3];
        r1 += (s0 < own1) + (s1 < own1) + (s2 < own1) + (s3 < own1);
    }
    if (r1 >= 1 && r1 <= KNN) {
        u32 fk = (u32)(own1 >> 32);
        u32 bb = (fk & 0x80000000u) ? (fk ^ 0x80000000u) : ~fk;
        edge_ws[(size_t)row * KNN + r1 - 1] = (u16)(u32)own1;
        dist_ws[(size_t)row * KNN + r1 - 1] = __uint_as_float(bb);
    }
    if (cnt > 64) {   // uncommon (~1%), wave-uniform
        u64 own2 = (64 + lane < cnt) ? sl[64 + lane] : ~0ull;
        int r2 = 0;
        for (int i = 0; i < cnt; i += 4) {
            u64 s0 = sl[i], s1 = sl[i + 1], s2 = sl[i + 2], s3 = sl[i + 3];
            r2 += (s0 < own2) + (s1 < own2) + (s2 < own2) + (s3 < own2);
        }
        if (r2 >= 1 && r2 <= KNN) {
            u32 fk = (u32)(own2 >> 32);
            u32 bb = (fk & 0x80000000u) ? (fk ^ 0x80000000u) : ~fk;
            edge_ws[(size_t)row * KNN + r2 - 1] = (u16)(u32)own2;
            dist_ws[(size_t)row * KNN + r2 - 1] = __uint_as_float(bb);
        }
    }
}

// same, for survivors stored descending from sl[127] (rowB of the shared buf)
__device__ __forceinline__ void emit_rank_rev(u64* sl, int cnt, int row, int lane,
                                              u16* __restrict__ edge_ws,
                                              float* __restrict__ dist_ws) {
    if (lane < 4) sl[127 - (cnt + lane)] = ~0ull;   // pads
    u64 own1 = sl[127 - lane];
    if (lane >= cnt) own1 = ~0ull;
    int r1 = 0;
    for (int i = 0; i < cnt; i += 4) {
        u64 s0 = sl[127 - i], s1 = sl[126 - i], s2 = sl[125 - i], s3 = sl[124 - i];
        r1 += (s0 < own1) + (s1 < own1) + (s2 < own1) + (s3 < own1);
    }
    if (r1 >= 1 && r1 <= KNN) {
        u32 fk = (u32)(own1 >> 32);
        u32 bb = (fk & 0x80000000u) ? (fk ^ 0x80000000u) : ~fk;
        edge_ws[(size_t)row * KNN + r1 - 1] = (u16)(u32)own1;
        dist_ws[(size_t)row * KNN + r1 - 1] = __uint_as_float(bb);
    }
    if (cnt > 64) {
        u64 own2 = (64 + lane < cnt) ? sl[127 - 64 - lane] : ~0ull;
        int r2 = 0;
        for (int i = 0; i < cnt; i += 4) {
            u64 s0 = sl[127 - i], s1 = sl[126 - i], s2 = sl[125 - i], s3 = sl[124 - i];
            r2 += (s0 < own2) + (s1 < own2) + (s2 < own2) + (s3 < own2);
        }
        if (r2 >= 1 && r2 <= KNN) {
            u32 fk = (u32)(own2 >> 32);
            u32 bb = (fk & 0x80000000u) ? (fk ^ 0x80000000u) : ~fk;
            edge_ws[(size_t)row * KNN + r2 - 1] = (u16)(u32)own2;
            dist_ws[(size_t)row * KNN + r2 - 1] = __uint_as_float(bb);
        }
    }
}

// register-light exact fallback (~never): 33 rescan-extract rounds
__device__ __attribute__((noinline)) void slow_row(const float4* sp, float4 me,
                                                   int row, int lane,
                                                   u16* __restrict__ edge_ws,
                                                   float* __restrict__ dist_ws) {
    u64 thr = 0ull;   // all real keys are > 0 (flip==0 would require NaN dist)
    for (int s = 0; s <= KNN; ++s) {
        u64 best = ~0ull;
        for (int jj = 0; jj < 32; ++jj) {
            int j = jj * 64 + lane;
            u64 x = dist_key(np_dist(me, sp[j]), j);
            if (x > thr && x < best) best = x;
        }
        u32 bh = (u32)(best >> 32);
        u32 rh = wave_min_dpp(bh);
        u32 bl = (bh == rh) ? (u32)best : 0xFFFFFFFFu;
        u32 rl = wave_min_dpp(bl);
        thr = ((u64)rh << 32) | rl;
        if (s >= 1 && lane == s - 1) {
            u32 bb = (rh & 0x80000000u) ? (rh ^ 0x80000000u) : ~rh;
            edge_ws[(size_t)row * KNN + s - 1] = (u16)rl;
            dist_ws[(size_t)row * KNN + s - 1] = __uint_as_float(bb);
        }
    }
}

// CHEAP fallback: one row's scalar re-compact into the full 128-slot buffer
// (R14 structure; guard 124 -> slow_row essentially never)
__device__ void compact_emit_seq(const float4* sp, float4 me, float pd,
                                 u64* sl, int row, int lane,
                                 u16* __restrict__ edge_ws,
                                 float* __restrict__ dist_ws) {
    u32 base = 0;
#pragma unroll 2
    for (int jj = 0; jj < 32; ++jj) {
        int j = jj * 64 + lane;
        float d = np_dist(me, sp[j]);
        bool s = d <= pd;
        u64 m = __ballot(s);
        u32 pos = base + mbcnt64(m);
        if (s && pos < 128) sl[pos] = ((u64)flip_bits(d) << 32) | (u32)j;
        base += (u32)__popcll(m);
    }
    if ((int)base <= 124) emit_rank(sl, (int)base, row, lane, edge_ws, dist_ws);
    else                  slow_row(sp, me, row, lane, edge_ws, dist_ws);
}

__global__ __launch_bounds__(512, 6) void knn_kernel(const float* __restrict__ pos,
                                                     u16* __restrict__ edge_ws,
                                                     float* __restrict__ dist_ws,
                                                     const float* __restrict__ aw,
                                                     const float* __restrict__ sw,
                                                     float* __restrict__ aw4,
                                                     float* __restrict__ sw4) {
    __shared__ float4 sp[N];          // 32 KB
    __shared__ u64 slots[8][128];     // 8 KB: rowA front / rowB back, per wave
    const int tid  = threadIdx.x;
    const int lane = tid & 63;
    const int wave = tid >> 6;          // 0..7
    const int rb   = blockIdx.x * 16;   // 16 rows per block, same (b,c)
    const int bc   = rb >> 11;

    const float* posr = pos + (size_t)bc * (N * 3);
    for (int j = tid; j < N; j += 512) {
        float x = posr[3 * j], y = posr[3 * j + 1], z = posr[3 * j + 2];
        sp[j] = make_float4(x, y, z, np_quad(x, y, z));
    }

    // fused prep (block 0 only): repack weights into [f/4][m][f%4]
    if (blockIdx.x == 0) {
#pragma unroll
        for (int it = 0; it < 16; ++it) {
            int i = it * 512 + tid;           // i = f*64 + m
            int f = i >> 6, mm = i & 63;
            int idx = (f >> 2) * 256 + mm * 4 + (f & 3);
            aw4[idx] = aw[mm * 128 + f];
            sw4[idx] = sw[i];
        }
    }
    __syncthreads();

    const int rowA = rb + wave * 2, rowB = rowA + 1;
    const int nA = rowA & (N - 1), nB = nA + 1;
    const float4 meA = sp[nA];
    const float4 meB = sp[nB];
    const v2f mex = {meA.x, meB.x};
    const v2f mey = {meA.y, meB.y};
    const v2f mez = {meA.z, meB.z};
    const v2f mew = {meA.w, meB.w};

    // ---- pass 1: packed per-lane float min of dists, both rows ----
    float mnA = __builtin_inff(), mnB = __builtin_inff();
#pragma unroll 8
    for (int jj = 0; jj < 32; ++jj) {
        int j = jj * 64 + lane;
        v2f d = np_dist2(mex, mey, mez, mew, sp[j]);
        mnA = fminf(mnA, d.x);
        mnB = fminf(mnB, d.y);
    }

    // ---- pivots: 33rd-smallest lane min (interleaved float bitonic) ----
    float vA = mnA, vB = mnB;
#pragma unroll
    for (int k = 2; k <= 64; k <<= 1) {
#pragma unroll
        for (int j = k >> 1; j > 0; j >>= 1) {
            float oA = __int_as_float(__shfl_xor(__float_as_int(vA), j));
            float oB = __int_as_float(__shfl_xor(__float_as_int(vB), j));
            bool keepmin = (((lane & k) == 0) == ((lane & j) == 0));
            vA = ((oA < vA) == keepmin) ? oA : vA;
            vB = ((oB < vB) == keepmin) ? oB : vB;
        }
    }
    float pdA = __int_as_float(__builtin_amdgcn_readlane(__float_as_int(vA), 32));
    float pdB = __int_as_float(__builtin_amdgcn_readlane(__float_as_int(vB), 32));

    // ---- pass 2: ONE packed scan; A compacts forward, B backward ----
    u64* sl = slots[wave];
    u32 baseA = 0, baseB = 0;
#pragma unroll 2
    for (int jj = 0; jj < 32; ++jj) {
        int j = jj * 64 + lane;
        v2f d = np_dist2(mex, mey, mez, mew, sp[j]);
        bool sA = d.x <= pdA;
        bool sB = d.y <= pdB;
        u64 mA = __ballot(sA);
        u64 mB = __ballot(sB);
        u32 posA = baseA + mbcnt64(mA);
        u32 posB = baseB + mbcnt64(mB);
        if (sA && posA < 128) sl[posA] = ((u64)flip_bits(d.x) << 32) | (u32)j;
        if (sB && posB < 128) sl[127 - posB] = ((u64)flip_bits(d.y) << 32) | (u32)j;
        baseA += (u32)__popcll(mA);
        baseB += (u32)__popcll(mB);
    }

    if (baseA + baseB <= 121) {   // pad-collision-free up to 124; margin 3
        emit_rank(sl, (int)baseA, rowA, lane, edge_ws, dist_ws);
        emit_rank_rev(sl, (int)baseB, rowB, lane, edge_ws, dist_ws);
    } else {
        // cheap fallback: sequential per-row re-compact (R14 form)
        compact_emit_seq(sp, meA, pdA, sl, rowA, lane, edge_ws, dist_ws);
        compact_emit_seq(sp, meB, pdB, sl, rowB, lane, edge_ws, dist_ws);
    }
}

// ---------------------------------------------------------------------------
// Kernel 2: angle features + gate + gated aggregation + two 128->64 matvecs.
// One wave per (b,n); 8 consecutive n (same b) per 512-thread block.
// All intermediates wave-private in LDS -> only ONE barrier (outv transpose).
// Phase C: float4 weights from global (VMEM pipe) x float4 theta/h broadcast
// from LDS, INTERLEAVED (R15's split-pass variant regressed ~6 us).
// ---------------------------------------------------------------------------
__global__ __launch_bounds__(512) void conv_kernel(
    const float* __restrict__ pos, const float* __restrict__ node_fea,
    const float* __restrict__ node_mask, const float* __restrict__ aw4,
    const float* __restrict__ sw4, const float* __restrict__ w1,
    const float* __restrict__ w2, const u16* __restrict__ edge_ws,
    const float* __restrict__ dist_ws, float* __restrict__ out) {
    __shared__ __align__(16) float theta_lds[8][128];  // [wave][f], f=kk*4+cc
    __shared__ float gate_lds[8][128];                 // [wave][cc*32+kk]
    __shared__ u16   edge_lds[8][128];                 // [wave][cc*32+kk]
    __shared__ __align__(16) float h_lds[8][128];      // [wave][f], f=cc*32+..
    __shared__ float gsum_lds[8][4];                   // [wave][cc]
    __shared__ float outv[8][65];                      // [n-offset][m], padded

    const int tid  = threadIdx.x;
    const int lane = tid & 63;
    const int wave = tid >> 6;             // 0..7

    const int row0 = blockIdx.x * 8;   // (b,n) row base, same b across block
    const int b    = row0 >> 11;
    const int n0   = row0 & (N - 1);
    const int row  = row0 + wave;
    const int n    = row & (N - 1);
    const float mval = node_mask[b * N + n];

    // gate scalar S = sum_m relu(w1[m]) * w2[m]
    float S = wave_sum_dpp(fmaxf(w1[lane], 0.f) * w2[lane]);

    // ---- Phase A: per (cc,kk) pair: direction, theta, gate (wave-private) ----
#pragma unroll
    for (int it = 0; it < 2; ++it) {
        int p  = it * 64 + lane;
        int cc = p >> 5, kk = p & 31;
        int rowc = (b * C + cc) * N + n;
        int e      = edge_ws[(size_t)rowc * KNN + kk];
        float dist = dist_ws[(size_t)rowc * KNN + kk];
        const float* pp = pos + (size_t)rowc * 3;
        const float* qp = pos + ((size_t)(b * C + cc) * N + e) * 3;
        float dx = qp[0] - pp[0], dy = qp[1] - pp[1], dz = qp[2] - pp[2];
        float nrm = fmaxf(sqrtf(dx * dx + dy * dy + dz * dz), 1e-12f);
        float inv = 1.0f / nrm;
        dx *= inv; dy *= inv; dz *= inv;
        int src = lane & 32;   // lane holding kk==0 for this cc-group
        float n0x = __shfl(dx, src), n0y = __shfl(dy, src), n0z = __shfl(dz, src);
        float cosv = (kk == 0) ? 1.f : (dx * n0x + dy * n0y + dz * n0z);
        theta_lds[wave][kk * 4 + cc] = cosv * mval;

        float g = fmaxf(dist * S, 0.f) * mval;
        float gate = 1.f / (1.f + expf(-g));
        gate_lds[wave][cc * 32 + kk] = gate;
        edge_lds[wave][cc * 32 + kk] = (u16)e;
        float gs = gate;
#pragma unroll
        for (int off = 1; off < 32; off <<= 1) gs += __shfl_xor(gs, off);
        if (kk == 0) gsum_lds[wave][cc] = gs;
    }

    // ---- Phase B: h[f] = sum_k gate * fea_cat (all 64 lanes gather) ----
    {
        int cc = lane >> 4, dd = lane & 15;
        const float* nf = node_fea + (size_t)(b * C + cc) * N * D;
        float own = nf[(size_t)n * D + dd];
        h_lds[wave][cc * 32 + dd] = own * mval * gsum_lds[wave][cc];
        float acc = 0.f;
#pragma unroll
        for (int k = 0; k < 32; ++k) {
            int e = edge_lds[wave][cc * 32 + k];
            acc += gate_lds[wave][cc * 32 + k] * nf[(size_t)e * D + dd];
        }
        h_lds[wave][cc * 32 + 16 + dd] = acc * mval;
    }

    // ---- Phase C: m = lane; two 128->64 matvecs (float4, interleaved) ----
    {
        const float4* wa4 = (const float4*)aw4;
        const float4* wv4 = (const float4*)sw4;
        const float4* th4 = (const float4*)(&theta_lds[wave][0]);
        const float4* hh4 = (const float4*)(&h_lds[wave][0]);
        float fs = 0.f, fe = 0.f;
#pragma unroll 4
        for (int f4 = 0; f4 < 32; ++f4) {
            float4 wa = wa4[f4 * 64 + lane];
            float4 wv = wv4[f4 * 64 + lane];
            float4 tv = th4[f4];
            float4 hv = hh4[f4];
            fs += wa.x * tv.x + wa.y * tv.y + wa.z * tv.z + wa.w * tv.w;
            fe += wv.x * hv.x + wv.y * hv.y + wv.z * hv.z + wv.w * hv.w;
        }
        float v = fs + fe;
        v = (v > 0.f) ? v : 0.01f * v;
        outv[wave][lane] = v * mval;
    }
    __syncthreads();   // the only cross-wave handoff (outv transpose)

    // store: thread t -> m = t>>3, n-offset j = t&7
    {
        int m = tid >> 3, j = tid & 7;
        out[((size_t)(b * 64 + m)) * N + n0 + j] = outv[j][m];
    }
}

// ---------------------------------------------------------------------------
extern "C" void kernel_launch(void* const* d_in, const int* in_sizes, int n_in,
                              void* d_out, int out_size, void* d_ws, size_t ws_size,
                              hipStream_t stream) {
    const float* pos       = (const float*)d_in[0];
    const float* node_fea  = (const float*)d_in[1];
    const float* node_mask = (const float*)d_in[2];
    const float* aw        = (const float*)d_in[3];
    const float* sw        = (const float*)d_in[4];
    const float* w1        = (const float*)d_in[5];
    const float* w2        = (const float*)d_in[6];
    float* out = (float*)d_out;

    // ws: dist f32 4 MB | edge u16 2 MB | aw4 32 KB | sw4 32 KB  (~6.1 MB)
    float* dist_ws = (float*)d_ws;
    u16*   edge_ws = (u16*)((char*)d_ws + 4u * 1024 * 1024);
    float* aw4     = (float*)((char*)d_ws + 6u * 1024 * 1024);
    float* sw4     = (float*)((char*)d_ws + 6u * 1024 * 1024 + 32u * 1024);

    knn_kernel<<<BS * C * N / 16, 512, 0, stream>>>(pos, edge_ws, dist_ws,
                                                    aw, sw, aw4, sw4);
    conv_kernel<<<BS * N / 8, 512, 0, stream>>>(pos, node_fea, node_mask, aw4, sw4,
                                                w1, w2, edge_ws, dist_ws, out);
}